// Round 10
// baseline (209.470 us; speedup 1.0000x reference)
//
#include <hip/hip_runtime.h>
#include <math.h>

typedef __attribute__((ext_vector_type(8))) short short8;
typedef __attribute__((ext_vector_type(4))) float floatx4;
typedef __attribute__((ext_vector_type(16))) float floatx16;

__device__ __forceinline__ unsigned short f2bf(float f) {
  union { float f; unsigned int u; } v; v.f = f;
  unsigned int r = v.u + 0x7fffu + ((v.u >> 16) & 1u);
  return (unsigned short)(r >> 16);
}

__device__ __forceinline__ float bf2f(unsigned short h) {
  union { unsigned int u; float f; } v; v.u = ((unsigned int)h) << 16;
  return v.f;
}

__device__ __forceinline__ unsigned int pack2(unsigned short a, unsigned short b) {
  return (unsigned int)a | ((unsigned int)b << 16);
}

__device__ __forceinline__ float fast_exp2(float x) {
#if __has_builtin(__builtin_amdgcn_exp2f)
  return __builtin_amdgcn_exp2f(x);
#else
  return exp2f(x);
#endif
}

// async global->LDS, 16B per lane. LDS dest is wave-uniform base + lane*16.
__device__ __forceinline__ void async16(const unsigned short* gp, unsigned short* lp) {
  __builtin_amdgcn_global_load_lds(
      (__attribute__((address_space(1))) void*)(gp),
      (__attribute__((address_space(3))) void*)(lp), 16, 0, 0);
}

// ------------------------------------------------- setup: GN stats + w casts
__global__ void setup_kernel(const float* __restrict__ x, float2* __restrict__ stats_p,
                             const float* __restrict__ qkv_w, unsigned short* __restrict__ wqkv,
                             const float* __restrict__ proj_w, unsigned short* __restrict__ wproj) {
  if (blockIdx.x < 512) {
    const int bid = blockIdx.x;
    const int bg  = bid >> 3;
    const int sub = bid & 7;
    const float4* p = (const float4*)(x + (size_t)bg * 65536 + (size_t)sub * 8192);
    float s = 0.f, ss = 0.f;
    #pragma unroll
    for (int i = 0; i < 8; i++) {
      float4 v = p[threadIdx.x + i*256];
      s  += v.x + v.y + v.z + v.w;
      ss += v.x*v.x + v.y*v.y + v.z*v.z + v.w*v.w;
    }
    #pragma unroll
    for (int off = 32; off >= 1; off >>= 1) {
      s  += __shfl_xor(s,  off, 64);
      ss += __shfl_xor(ss, off, 64);
    }
    __shared__ float red[2][4];
    int wv = threadIdx.x >> 6;
    if ((threadIdx.x & 63) == 0) { red[0][wv] = s; red[1][wv] = ss; }
    __syncthreads();
    if (threadIdx.x == 0) {
      s  = red[0][0] + red[0][1] + red[0][2] + red[0][3];
      ss = red[1][0] + red[1][1] + red[1][2] + red[1][3];
      stats_p[bid] = make_float2(s, ss);
    }
  } else {
    int i = (blockIdx.x - 512) * 256 + threadIdx.x;
    const float* s; unsigned short* d;
    if (i < 196608) { s = qkv_w; d = wqkv; }
    else { i -= 196608; s = proj_w; d = wproj; }
    float4 vv = ((const float4*)s)[i];
    uint2 o;
    o.x = pack2(f2bf(vv.x), f2bf(vv.y));
    o.y = pack2(f2bf(vv.z), f2bf(vv.w));
    ((uint2*)d)[i] = o;
  }
}

// normalize + cast bf16 + transpose to token-major h_t[B][HW][C]
__global__ void gn_apply_t(const float* __restrict__ x, const float2* __restrict__ stats_p,
                           const float* __restrict__ gw, const float* __restrict__ gb,
                           unsigned short* __restrict__ h_t) {
  __shared__ __align__(16) unsigned short tile[64][72];
  const int b = blockIdx.z, c0 = blockIdx.y * 64, hw0 = blockIdx.x * 64;
  const int t = threadIdx.x;
  {
    const int cl = t >> 2;
    const int hs = (t & 3) * 16;
    const int c  = c0 + cl;
    const int g  = c >> 4;
    const float2* sp = stats_p + ((size_t)(b*32 + g) << 3);
    float s = 0.f, ss = 0.f;
    #pragma unroll
    for (int k = 0; k < 8; k++) { float2 v = sp[k]; s += v.x; ss += v.y; }
    const float mean = s * (1.f/65536.f);
    const float var  = ss * (1.f/65536.f) - mean*mean;
    const float rstd = rsqrtf(var + 1e-5f);
    const float w  = gw[c] * rstd;
    const float bb = gb[c] - mean * w;
    const float4* src = (const float4*)(x + ((size_t)(b*512 + c))*4096 + hw0 + hs);
    #pragma unroll
    for (int i = 0; i < 4; i++) {
      float4 vv = src[i];
      unsigned short* d = &tile[cl][hs + i*4];
      d[0] = f2bf(vv.x*w + bb); d[1] = f2bf(vv.y*w + bb);
      d[2] = f2bf(vv.z*w + bb); d[3] = f2bf(vv.w*w + bb);
    }
  }
  __syncthreads();
  {
    const int hwl = t >> 2;
    const int cs  = (t & 3) * 16;
    uint4 w0, w1;
    w0.x = pack2(tile[cs+ 0][hwl], tile[cs+ 1][hwl]);
    w0.y = pack2(tile[cs+ 2][hwl], tile[cs+ 3][hwl]);
    w0.z = pack2(tile[cs+ 4][hwl], tile[cs+ 5][hwl]);
    w0.w = pack2(tile[cs+ 6][hwl], tile[cs+ 7][hwl]);
    w1.x = pack2(tile[cs+ 8][hwl], tile[cs+ 9][hwl]);
    w1.y = pack2(tile[cs+10][hwl], tile[cs+11][hwl]);
    w1.z = pack2(tile[cs+12][hwl], tile[cs+13][hwl]);
    w1.w = pack2(tile[cs+14][hwl], tile[cs+15][hwl]);
    unsigned short* dst = h_t + ((size_t)(b*4096 + hw0 + hwl))*512 + c0 + cs;
    *(uint4*)dst       = w0;
    *(uint4*)(dst + 8) = w1;
  }
}

// ---------------------------------------------------------------- QKV GEMM
// R7 config: BK=32, no XCD swizzle (swizzle regressed ~4us: R9).
__global__ __launch_bounds__(256, 3)
void qkv_gemm(const unsigned short* __restrict__ A,
              const unsigned short* __restrict__ Bt,
              unsigned short* __restrict__ q_t,
              unsigned short* __restrict__ k_t,
              unsigned short* __restrict__ v_) {
  __shared__ __align__(16) unsigned short As[128*32];
  __shared__ __align__(16) unsigned short Bs[128*32];
  const int b   = blockIdx.z;
  const int n0  = blockIdx.x * 128;
  const int o0  = blockIdx.y * 128;
  const int tid = threadIdx.x;
  const int wave = tid >> 6, lane = tid & 63;
  const int wr = wave >> 1, wc = wave & 1;
  const int fm = lane & 15, fq = lane >> 4;
  const int srow = lane >> 2, scol = (lane & 3) * 8;

  const unsigned short* Ab = A + (size_t)o0 * 512;
  const unsigned short* Bb = Bt + ((size_t)b*4096 + n0) * 512;

  bool vsw[4];
  #pragma unroll
  for (int fr = 0; fr < 4; fr++) {
    const int ob = o0 + wr*64 + fr*16;
    vsw[fr] = ((ob % 192) >> 6) == 2;
  }

  floatx4 acc[4][4];
  #pragma unroll
  for (int i = 0; i < 4; i++)
    #pragma unroll
    for (int j = 0; j < 4; j++) acc[i][j] = (floatx4){0.f,0.f,0.f,0.f};

  for (int k0 = 0; k0 < 512; k0 += 32) {
    __syncthreads();
    #pragma unroll
    for (int cc = 0; cc < 2; cc++) {
      int ch = wave*2 + cc;
      async16(Ab + (size_t)(ch*16 + srow)*512 + k0 + scol, &As[ch*512]);
      async16(Bb + (size_t)(ch*16 + srow)*512 + k0 + scol, &Bs[ch*512]);
    }
    __syncthreads();
    short8 af[4], bf[4];
    #pragma unroll
    for (int f = 0; f < 4; f++) {
      af[f] = *(const short8*)&As[(wr*64 + f*16 + fm)*32 + fq*8];
      bf[f] = *(const short8*)&Bs[(wc*64 + f*16 + fm)*32 + fq*8];
    }
    #pragma unroll
    for (int fr = 0; fr < 4; fr++) {
      if (vsw[fr]) {
        #pragma unroll
        for (int fc = 0; fc < 4; fc++)
          acc[fr][fc] = __builtin_amdgcn_mfma_f32_16x16x32_bf16(bf[fc], af[fr], acc[fr][fc], 0, 0, 0);
      } else {
        #pragma unroll
        for (int fc = 0; fc < 4; fc++)
          acc[fr][fc] = __builtin_amdgcn_mfma_f32_16x16x32_bf16(af[fr], bf[fc], acc[fr][fc], 0, 0, 0);
      }
    }
  }

  #pragma unroll
  for (int fr = 0; fr < 4; fr++) {
    const int ob     = o0 + wr*64 + fr*16;
    const int head   = ob / 192;
    const int rem    = ob % 192;
    const int region = rem >> 6;             // 0=q 1=k 2=v
    const int bhh    = b*8 + head;
    #pragma unroll
    for (int fc = 0; fc < 4; fc++) {
      if (region == 0) {
        const int i = n0 + wc*64 + fc*16 + fm;
        const int dsub = (rem & 63) + fq*4;
        unsigned short t4[4];
        #pragma unroll
        for (int r = 0; r < 4; r++) t4[r] = f2bf(acc[fr][fc][r] * 0.18033688f);
        uint2 o; o.x = pack2(t4[0], t4[1]); o.y = pack2(t4[2], t4[3]);
        *(uint2*)&q_t[((size_t)bhh*4096 + i)*64 + dsub] = o;
      } else if (region == 1) {
        const int i = n0 + wc*64 + fc*16 + fm;
        const int dsub = (rem & 63) + fq*4;
        unsigned short t4[4];
        #pragma unroll
        for (int r = 0; r < 4; r++) t4[r] = f2bf(acc[fr][fc][r]);
        uint2 o; o.x = pack2(t4[0], t4[1]); o.y = pack2(t4[2], t4[3]);
        *(uint2*)&k_t[((size_t)bhh*4096 + i)*64 + dsub] = o;
      } else {
        const int dsub = (rem & 63) + fm;
        const int tok0 = n0 + wc*64 + fc*16 + fq*4;
        unsigned short t4[4];
        #pragma unroll
        for (int r = 0; r < 4; r++) t4[r] = f2bf(acc[fr][fc][r]);
        uint2 o; o.x = pack2(t4[0], t4[1]); o.y = pack2(t4[2], t4[3]);
        *(uint2*)&v_[((size_t)bhh*64 + dsub)*4096 + tok0] = o;
      }
    }
  }
}

// ---------------------------------------------------------------- proj GEMM
// R7 config: BK=32, no XCD swizzle.
__global__ __launch_bounds__(256, 2)
void proj_gemm(const unsigned short* __restrict__ A,     // wproj [512][512]
               const unsigned short* __restrict__ Bt,    // hout_t [B][4096][512]
               float* __restrict__ outp,
               const float* __restrict__ xres,
               const float* __restrict__ pbias) {
  __shared__ __align__(16) unsigned short As[64*32];
  __shared__ __align__(16) unsigned short Bs[128*32];
  const int b   = blockIdx.z;
  const int n0  = blockIdx.x * 128;
  const int o0  = blockIdx.y * 64;
  const int tid = threadIdx.x;
  const int wave = tid >> 6, lane = tid & 63;
  const int wr = wave >> 1, wc = wave & 1;
  const int fm = lane & 15, fq = lane >> 4;
  const int srow = lane >> 2, scol = (lane & 3) * 8;

  const unsigned short* Ab = A + (size_t)o0 * 512;
  const unsigned short* Bb = Bt + ((size_t)b*4096 + n0) * 512;

  floatx4 acc[2][4];
  #pragma unroll
  for (int i = 0; i < 2; i++)
    #pragma unroll
    for (int j = 0; j < 4; j++) acc[i][j] = (floatx4){0.f,0.f,0.f,0.f};

  for (int k0 = 0; k0 < 512; k0 += 32) {
    __syncthreads();
    async16(Ab + (size_t)(wave*16 + srow)*512 + k0 + scol, &As[wave*512]);
    #pragma unroll
    for (int cc = 0; cc < 2; cc++) {
      int ch = wave*2 + cc;
      async16(Bb + (size_t)(ch*16 + srow)*512 + k0 + scol, &Bs[ch*512]);
    }
    __syncthreads();
    short8 af[2], bf[4];
    #pragma unroll
    for (int f = 0; f < 2; f++)
      af[f] = *(const short8*)&As[(wr*32 + f*16 + fm)*32 + fq*8];
    #pragma unroll
    for (int f = 0; f < 4; f++)
      bf[f] = *(const short8*)&Bs[(wc*64 + f*16 + fm)*32 + fq*8];
    #pragma unroll
    for (int fr = 0; fr < 2; fr++)
      #pragma unroll
      for (int fc = 0; fc < 4; fc++)
        acc[fr][fc] = __builtin_amdgcn_mfma_f32_16x16x32_bf16(af[fr], bf[fc], acc[fr][fc], 0, 0, 0);
  }

  #pragma unroll
  for (int fr = 0; fr < 2; fr++)
    #pragma unroll
    for (int fc = 0; fc < 4; fc++) {
      const int i = n0 + wc*64 + fc*16 + fm;
      #pragma unroll
      for (int r = 0; r < 4; r++) {
        const int o = o0 + wr*32 + fr*16 + fq*4 + r;
        const size_t idx = ((size_t)b*512 + o)*4096 + i;
        outp[idx] = xres[idx] + pbias[o] + acc[fr][fc][r];
      }
    }
}

// ---------------------------------------------------------------- attention
// 32 q-rows per wave (vs 64 in R3/R7): halves o_acc (64->32 AGPR) and qf
// (32->16 VGPR) so the wave fits the 170-reg cap of launch_bounds(256,3)
// -> 3 blocks/CU, 12 waves/CU (R7 was register-pinned at 2 blocks/CU with
// MfmaUtil+VALUBusy = 86%, ~14% dual-idle = occupancy-starved).
// Same proven pieces: pipelined QK-ahead, full-rate 32x32x16 PV via
// permlane32_swap, scalar VALU l-accumulate, [64][72]-padded reg-staged
// K/V double-buffer (0 conflicts). Grid (16, 32, NSPLIT); NSPLIT=3 gives
// 1536 blocks = two balanced rounds of 3/CU.

__device__ __forceinline__ void plswap(unsigned &a, unsigned &b) {
  asm("v_permlane32_swap_b32 %0, %1" : "+v"(a), "+v"(b));
}

__device__ __forceinline__ floatx16 qk4(const short8* kf, const short8* qf) {
  const floatx16 z16 = {0.f,0.f,0.f,0.f,0.f,0.f,0.f,0.f,
                        0.f,0.f,0.f,0.f,0.f,0.f,0.f,0.f};
  floatx16 st = __builtin_amdgcn_mfma_f32_32x32x16_bf16(kf[0], qf[0], z16, 0, 0, 0);
  #pragma unroll
  for (int kc = 1; kc < 4; kc++)
    st = __builtin_amdgcn_mfma_f32_32x32x16_bf16(kf[kc], qf[kc], st, 0, 0, 0);
  return st;
}

__device__ __forceinline__ void sm8(const floatx16 st, unsigned* pk, float2& lp) {
  #pragma unroll
  for (int rp = 0; rp < 8; rp++) {
    float p0 = fast_exp2(st[2*rp]);
    float p1 = fast_exp2(st[2*rp + 1]);
    lp.x += p0; lp.y += p1;
    unsigned r;
    asm("v_cvt_pk_bf16_f32 %0, %1, %2" : "=v"(r) : "v"(p0), "v"(p1));
    pk[rp] = r;
  }
}

// PV over one 32-j block: O[i][d] += sum_j P[i][j] V[j][d].
__device__ __forceinline__ void pv16(const unsigned* pk,
                                     const short8 vA0, const short8 vA1,
                                     const short8 vB0, const short8 vB1,
                                     floatx16* o) {
  unsigned a0 = pk[0], a2 = pk[2]; plswap(a0, a2);
  unsigned a1 = pk[1], a3 = pk[3]; plswap(a1, a3);
  unsigned b0 = pk[4], b2 = pk[6]; plswap(b0, b2);
  unsigned b1 = pk[5], b3 = pk[7]; plswap(b1, b3);
  union { unsigned u[4]; short8 s; } lo, hi;
  lo.u[0] = a0; lo.u[1] = a1; lo.u[2] = a2; lo.u[3] = a3;
  hi.u[0] = b0; hi.u[1] = b1; hi.u[2] = b2; hi.u[3] = b3;
  o[0] = __builtin_amdgcn_mfma_f32_32x32x16_bf16(lo.s, vA0, o[0], 0, 0, 0);
  o[0] = __builtin_amdgcn_mfma_f32_32x32x16_bf16(hi.s, vB0, o[0], 0, 0, 0);
  o[1] = __builtin_amdgcn_mfma_f32_32x32x16_bf16(lo.s, vA1, o[1], 0, 0, 0);
  o[1] = __builtin_amdgcn_mfma_f32_32x32x16_bf16(hi.s, vB1, o[1], 0, 0, 0);
}

template <int NSPLIT>
__global__ __launch_bounds__(256, 3)
void attn_kernel(const unsigned short* __restrict__ q_t,
                 const unsigned short* __restrict__ k_t,
                 const unsigned short* __restrict__ v_,
                 unsigned short* __restrict__ hout_t,
                 unsigned short* __restrict__ o_part,
                 float* __restrict__ l_part) {
  __shared__ __align__(16) unsigned short Ks[2][64*72];   // [j][k], +pad
  __shared__ __align__(16) unsigned short Vs[2][64*72];   // [d][j] linear, +pad

  const int bh  = blockIdx.x;
  const int q0  = blockIdx.y * 128;
  const int js  = (NSPLIT > 1) ? blockIdx.z : 0;
  const int t0  = (js * 64) / NSPLIT;
  const int t1  = ((js + 1) * 64) / NSPLIT;
  const int nt  = t1 - t0;
  const int jbase = t0 * 64;
  const int tid = threadIdx.x;
  const int wave = tid >> 6, lane = tid & 63;
  const int ln = lane & 31, h = lane >> 5;

  // Q B-frags (32x32x16): token i = q0 + wave*32 + ln
  short8 qf[4];
  {
    const unsigned short* qrow = q_t + ((size_t)bh*4096 + q0 + wave*32 + ln)*64;
    #pragma unroll
    for (int kc = 0; kc < 4; kc++)
      qf[kc] = *(const short8*)(qrow + kc*16 + h*8);
  }

  const floatx16 z16 = {0.f,0.f,0.f,0.f,0.f,0.f,0.f,0.f,
                        0.f,0.f,0.f,0.f,0.f,0.f,0.f,0.f};
  floatx16 o_acc[2];   // [dn]
  o_acc[0] = z16; o_acc[1] = z16;
  float2 lp = {0.f, 0.f};

  const int sr = tid >> 3;          // 0..31
  const int sc = (tid & 7) * 8;     // source 8-short chunk
  const unsigned short* kbase = k_t + (size_t)bh*262144;
  const unsigned short* vbase = v_  + (size_t)bh*262144;

  // preload tile 0 into registers
  uint4 kr0 = *(const uint4*)&kbase[(size_t)(jbase + sr)*64 + sc];
  uint4 kr1 = *(const uint4*)&kbase[(size_t)(jbase + sr + 32)*64 + sc];
  uint4 vr0 = *(const uint4*)&vbase[(size_t)sr*4096 + jbase + sc];
  uint4 vr1 = *(const uint4*)&vbase[(size_t)(sr+32)*4096 + jbase + sc];

  for (int it = 0; it < nt; it++) {
    unsigned short* Kc = Ks[it & 1];
    unsigned short* Vc = Vs[it & 1];
    *(uint4*)&Kc[sr*72 + sc]      = kr0;
    *(uint4*)&Kc[(sr+32)*72 + sc] = kr1;
    *(uint4*)&Vc[sr*72 + sc]      = vr0;
    *(uint4*)&Vc[(sr+32)*72 + sc] = vr1;
    __syncthreads();

    // issue next tile's global loads (latency hidden behind compute)
    {
      int itn = it + 1; if (itn == nt) itn = 0;
      const int jn = (t0 + itn) * 64;
      kr0 = *(const uint4*)&kbase[(size_t)(jn + sr)*64 + sc];
      kr1 = *(const uint4*)&kbase[(size_t)(jn + sr + 32)*64 + sc];
      vr0 = *(const uint4*)&vbase[(size_t)sr*4096 + jn + sc];
      vr1 = *(const uint4*)&vbase[(size_t)(sr+32)*4096 + jn + sc];
    }

    // mj=0 frags
    short8 kf0[4];
    #pragma unroll
    for (int kc = 0; kc < 4; kc++)
      kf0[kc] = *(const short8*)&Kc[(0*32 + ln)*72 + kc*16 + h*8];
    short8 vA0[2], vB0[2];
    #pragma unroll
    for (int dn = 0; dn < 2; dn++) {
      vA0[dn] = *(const short8*)&Vc[(dn*32 + ln)*72 + 0*32 + h*8];
      vB0[dn] = *(const short8*)&Vc[(dn*32 + ln)*72 + 0*32 + 16 + h*8];
    }

    // prologue: QK(mj0)
    floatx16 stA = qk4(kf0, qf);

    // step 0: QK(mj1) || softmax(stA) ; PV(mj0)
    short8 kf1[4];
    #pragma unroll
    for (int kc = 0; kc < 4; kc++)
      kf1[kc] = *(const short8*)&Kc[(1*32 + ln)*72 + kc*16 + h*8];
    floatx16 stB = qk4(kf1, qf);
    unsigned pkA[8];
    sm8(stA, pkA, lp);
    pv16(pkA, vA0[0], vA0[1], vB0[0], vB0[1], o_acc);

    // step 1 (tail): mj=1 V-frags; softmax(stB) ; PV(mj1)
    short8 vA1[2], vB1[2];
    #pragma unroll
    for (int dn = 0; dn < 2; dn++) {
      vA1[dn] = *(const short8*)&Vc[(dn*32 + ln)*72 + 1*32 + h*8];
      vB1[dn] = *(const short8*)&Vc[(dn*32 + ln)*72 + 1*32 + 16 + h*8];
    }
    unsigned pkB[8];
    sm8(stB, pkB, lp);
    pv16(pkB, vA1[0], vA1[1], vB1[0], vB1[1], o_acc);
  }

  // column sums complete within lane pairs (h=0/1)
  float l = lp.x + lp.y;
  l += __shfl_xor(l, 32, 64);

  if (NSPLIT > 1) {
    unsigned short* op = o_part +
        (((size_t)(js*16 + bh)*4096 + q0 + wave*32) * 64);
    #pragma unroll
    for (int r = 0; r < 16; r++) {
      const int il = (r & 3) + 8*(r >> 2) + 4*h;   // token row within 32
      op[(size_t)il*64 + ln]      = f2bf(o_acc[0][r]);
      op[(size_t)il*64 + 32 + ln] = f2bf(o_acc[1][r]);
    }
    if (lane < 32)
      l_part[(size_t)(js*16 + bh)*4096 + q0 + wave*32 + lane] = l;
  } else {
    const float linv = 1.f / l;
    const int bb = bh >> 3;
    const int cb = (bh & 7) * 64;
    #pragma unroll
    for (int r = 0; r < 16; r++) {
      const int il = (r & 3) + 8*(r >> 2) + 4*h;
      const float inv = __shfl(linv, il, 64);
      const int i = q0 + wave*32 + il;
      unsigned short* dst = &hout_t[((size_t)bb*4096 + i)*512 + cb + ln];
      dst[0]  = f2bf(o_acc[0][r] * inv);
      dst[32] = f2bf(o_acc[1][r] * inv);
    }
  }
}

// combine: hout = (sum_ns O_ns)/(sum_ns l_ns), bf16 token-major
__global__ void attn_combine(const unsigned short* __restrict__ o_part,
                             const float* __restrict__ l_part,
                             unsigned short* __restrict__ hout_t,
                             int nsplit) {
  const int bh = blockIdx.x;
  const int i0 = blockIdx.y * 64;
  const int t  = threadIdx.x;
  const int d4 = (t & 15) * 4;
  const int il = t >> 4;
  const int bb = bh >> 3;
  const int cb = (bh & 7) * 64;
  const size_t JS = (size_t)16 * 4096 * 64;   // js stride in o_part (shorts)
  const size_t LS = (size_t)16 * 4096;        // js stride in l_part (floats)
  #pragma unroll
  for (int p = 0; p < 4; p++) {
    const int i = i0 + p*16 + il;
    float o0 = 0.f, o1 = 0.f, o2 = 0.f, o3 = 0.f, l = 0.f;
    for (int ns = 0; ns < nsplit; ns++) {
      const size_t ob = ((size_t)bh*4096 + i)*64 + d4 + (size_t)ns*JS;
      uint2 a = *(const uint2*)&o_part[ob];
      o0 += bf2f((unsigned short)(a.x & 0xffff));
      o1 += bf2f((unsigned short)(a.x >> 16));
      o2 += bf2f((unsigned short)(a.y & 0xffff));
      o3 += bf2f((unsigned short)(a.y >> 16));
      l  += l_part[(size_t)bh*4096 + i + (size_t)ns*LS];
    }
    const float inv = 1.f / l;
    uint2 w;
    w.x = pack2(f2bf(o0 * inv), f2bf(o1 * inv));
    w.y = pack2(f2bf(o2 * inv), f2bf(o3 * inv));
    *(uint2*)&hout_t[((size_t)bb*4096 + i)*512 + cb + d4] = w;
  }
}

// ---------------------------------------------------------------- launcher
extern "C" void kernel_launch(void* const* d_in, const int* in_sizes, int n_in,
                              void* d_out, int out_size, void* d_ws, size_t ws_size,
                              hipStream_t stream) {
  (void)in_sizes; (void)n_in; (void)out_size;
  const float* x      = (const float*)d_in[0];
  const float* qkv_w  = (const float*)d_in[1];
  const float* proj_w = (const float*)d_in[2];
  const float* proj_b = (const float*)d_in[3];
  const float* gn_w   = (const float*)d_in[4];
  const float* gn_b   = (const float*)d_in[5];
  float* out = (float*)d_out;

  char* ws = (char*)d_ws;
  unsigned short* h_t   = (unsigned short*)(ws);                      // 8 MB, reused as hout_t
  unsigned short* q_t   = (unsigned short*)(ws + ((size_t)8  << 20));
  unsigned short* k_t   = (unsigned short*)(ws + ((size_t)16 << 20));
  unsigned short* v_    = (unsigned short*)(ws + ((size_t)24 << 20));
  unsigned short* wqkv  = (unsigned short*)(ws + ((size_t)32 << 20));
  unsigned short* wproj = (unsigned short*)(ws + ((size_t)34 << 20));
  float2* stats_p       = (float2*)(ws + ((size_t)35 << 20));
  unsigned short* hout_t = h_t;

  const size_t base      = (size_t)36 << 20;
  const size_t opart_per = (size_t)8 << 20;    // 16*4096*64*2 B per split
  const size_t lpart_per = (size_t)1 << 18;    // 16*4096*4 B per split
  int nsplit = 1;
  if      (ws_size >= base + 3*(opart_per + lpart_per)) nsplit = 3;
  else if (ws_size >= base + 2*(opart_per + lpart_per)) nsplit = 2;

  unsigned short* o_part = (unsigned short*)(ws + base);
  float* l_part          = (float*)(ws + base + (size_t)nsplit * opart_per);

  setup_kernel<<<dim3(1536), dim3(256), 0, stream>>>(x, stats_p, qkv_w, wqkv, proj_w, wproj);
  gn_apply_t<<<dim3(64, 8, 2), dim3(256), 0, stream>>>(x, stats_p, gn_w, gn_b, h_t);
  qkv_gemm<<<dim3(32, 12, 2), dim3(256), 0, stream>>>(wqkv, h_t, q_t, k_t, v_);
  switch (nsplit) {
    case 3:
      attn_kernel<3><<<dim3(16, 32, 3), dim3(256), 0, stream>>>(q_t, k_t, v_, nullptr,
                                                                o_part, l_part);
      break;
    case 2:
      attn_kernel<2><<<dim3(16, 32, 2), dim3(256), 0, stream>>>(q_t, k_t, v_, nullptr,
                                                                o_part, l_part);
      break;
    default:
      attn_kernel<1><<<dim3(16, 32), dim3(256), 0, stream>>>(q_t, k_t, v_, hout_t,
                                                             nullptr, nullptr);
      break;
  }
  if (nsplit > 1)
    attn_combine<<<dim3(16, 64), dim3(256), 0, stream>>>(o_part, l_part, hout_t, nsplit);
  proj_gemm<<<dim3(32, 8, 2), dim3(256), 0, stream>>>(wproj, hout_t, out, x, proj_b);
}

// Round 11
// 195.738 us; speedup vs baseline: 1.0702x; 1.0702x over previous
//
#include <hip/hip_runtime.h>
#include <math.h>

typedef __attribute__((ext_vector_type(8))) short short8;
typedef __attribute__((ext_vector_type(4))) float floatx4;
typedef __attribute__((ext_vector_type(16))) float floatx16;

__device__ __forceinline__ unsigned short f2bf(float f) {
  union { float f; unsigned int u; } v; v.f = f;
  unsigned int r = v.u + 0x7fffu + ((v.u >> 16) & 1u);
  return (unsigned short)(r >> 16);
}

__device__ __forceinline__ float bf2f(unsigned short h) {
  union { unsigned int u; float f; } v; v.u = ((unsigned int)h) << 16;
  return v.f;
}

__device__ __forceinline__ unsigned int pack2(unsigned short a, unsigned short b) {
  return (unsigned int)a | ((unsigned int)b << 16);
}

__device__ __forceinline__ float fast_exp2(float x) {
#if __has_builtin(__builtin_amdgcn_exp2f)
  return __builtin_amdgcn_exp2f(x);
#else
  return exp2f(x);
#endif
}

// async global->LDS, 16B per lane. LDS dest is wave-uniform base + lane*16.
__device__ __forceinline__ void async16(const unsigned short* gp, unsigned short* lp) {
  __builtin_amdgcn_global_load_lds(
      (__attribute__((address_space(1))) void*)(gp),
      (__attribute__((address_space(3))) void*)(lp), 16, 0, 0);
}

// ------------------------------------------------- setup: GN stats + w casts
// Stats parallelized: 512 blocks (8 sub-blocks per (b,group), 128KB each)
// write float2{sum, sumsq} partials; gn_apply_t folds the 8 partials.
__global__ void setup_kernel(const float* __restrict__ x, float2* __restrict__ stats_p,
                             const float* __restrict__ qkv_w, unsigned short* __restrict__ wqkv,
                             const float* __restrict__ proj_w, unsigned short* __restrict__ wproj) {
  if (blockIdx.x < 512) {
    const int bid = blockIdx.x;
    const int bg  = bid >> 3;
    const int sub = bid & 7;
    const float4* p = (const float4*)(x + (size_t)bg * 65536 + (size_t)sub * 8192);
    float s = 0.f, ss = 0.f;
    #pragma unroll
    for (int i = 0; i < 8; i++) {
      float4 v = p[threadIdx.x + i*256];
      s  += v.x + v.y + v.z + v.w;
      ss += v.x*v.x + v.y*v.y + v.z*v.z + v.w*v.w;
    }
    #pragma unroll
    for (int off = 32; off >= 1; off >>= 1) {
      s  += __shfl_xor(s,  off, 64);
      ss += __shfl_xor(ss, off, 64);
    }
    __shared__ float red[2][4];
    int wv = threadIdx.x >> 6;
    if ((threadIdx.x & 63) == 0) { red[0][wv] = s; red[1][wv] = ss; }
    __syncthreads();
    if (threadIdx.x == 0) {
      s  = red[0][0] + red[0][1] + red[0][2] + red[0][3];
      ss = red[1][0] + red[1][1] + red[1][2] + red[1][3];
      stats_p[bid] = make_float2(s, ss);
    }
  } else {
    int i = (blockIdx.x - 512) * 256 + threadIdx.x;
    const float* s; unsigned short* d;
    if (i < 196608) { s = qkv_w; d = wqkv; }
    else { i -= 196608; s = proj_w; d = wproj; }
    float4 vv = ((const float4*)s)[i];
    uint2 o;
    o.x = pack2(f2bf(vv.x), f2bf(vv.y));
    o.y = pack2(f2bf(vv.z), f2bf(vv.w));
    ((uint2*)d)[i] = o;
  }
}

// normalize + cast bf16 + transpose to token-major h_t[B][HW][C]
__global__ void gn_apply_t(const float* __restrict__ x, const float2* __restrict__ stats_p,
                           const float* __restrict__ gw, const float* __restrict__ gb,
                           unsigned short* __restrict__ h_t) {
  __shared__ __align__(16) unsigned short tile[64][72];
  const int b = blockIdx.z, c0 = blockIdx.y * 64, hw0 = blockIdx.x * 64;
  const int t = threadIdx.x;
  {
    const int cl = t >> 2;
    const int hs = (t & 3) * 16;
    const int c  = c0 + cl;
    const int g  = c >> 4;
    const float2* sp = stats_p + ((size_t)(b*32 + g) << 3);
    float s = 0.f, ss = 0.f;
    #pragma unroll
    for (int k = 0; k < 8; k++) { float2 v = sp[k]; s += v.x; ss += v.y; }
    const float mean = s * (1.f/65536.f);
    const float var  = ss * (1.f/65536.f) - mean*mean;
    const float rstd = rsqrtf(var + 1e-5f);
    const float w  = gw[c] * rstd;
    const float bb = gb[c] - mean * w;
    const float4* src = (const float4*)(x + ((size_t)(b*512 + c))*4096 + hw0 + hs);
    #pragma unroll
    for (int i = 0; i < 4; i++) {
      float4 vv = src[i];
      unsigned short* d = &tile[cl][hs + i*4];
      d[0] = f2bf(vv.x*w + bb); d[1] = f2bf(vv.y*w + bb);
      d[2] = f2bf(vv.z*w + bb); d[3] = f2bf(vv.w*w + bb);
    }
  }
  __syncthreads();
  {
    const int hwl = t >> 2;
    const int cs  = (t & 3) * 16;
    uint4 w0, w1;
    w0.x = pack2(tile[cs+ 0][hwl], tile[cs+ 1][hwl]);
    w0.y = pack2(tile[cs+ 2][hwl], tile[cs+ 3][hwl]);
    w0.z = pack2(tile[cs+ 4][hwl], tile[cs+ 5][hwl]);
    w0.w = pack2(tile[cs+ 6][hwl], tile[cs+ 7][hwl]);
    w1.x = pack2(tile[cs+ 8][hwl], tile[cs+ 9][hwl]);
    w1.y = pack2(tile[cs+10][hwl], tile[cs+11][hwl]);
    w1.z = pack2(tile[cs+12][hwl], tile[cs+13][hwl]);
    w1.w = pack2(tile[cs+14][hwl], tile[cs+15][hwl]);
    unsigned short* dst = h_t + ((size_t)(b*4096 + hw0 + hwl))*512 + c0 + cs;
    *(uint4*)dst       = w0;
    *(uint4*)(dst + 8) = w1;
  }
}

// ---------------------------------------------------------------- QKV GEMM
// R7 config: BK=32 (BK=64 regressed: R8), no XCD swizzle (regressed: R9).
__global__ __launch_bounds__(256, 3)
void qkv_gemm(const unsigned short* __restrict__ A,
              const unsigned short* __restrict__ Bt,
              unsigned short* __restrict__ q_t,
              unsigned short* __restrict__ k_t,
              unsigned short* __restrict__ v_) {
  __shared__ __align__(16) unsigned short As[128*32];
  __shared__ __align__(16) unsigned short Bs[128*32];
  const int b   = blockIdx.z;
  const int n0  = blockIdx.x * 128;
  const int o0  = blockIdx.y * 128;
  const int tid = threadIdx.x;
  const int wave = tid >> 6, lane = tid & 63;
  const int wr = wave >> 1, wc = wave & 1;
  const int fm = lane & 15, fq = lane >> 4;
  const int srow = lane >> 2, scol = (lane & 3) * 8;

  const unsigned short* Ab = A + (size_t)o0 * 512;
  const unsigned short* Bb = Bt + ((size_t)b*4096 + n0) * 512;

  bool vsw[4];
  #pragma unroll
  for (int fr = 0; fr < 4; fr++) {
    const int ob = o0 + wr*64 + fr*16;
    vsw[fr] = ((ob % 192) >> 6) == 2;
  }

  floatx4 acc[4][4];
  #pragma unroll
  for (int i = 0; i < 4; i++)
    #pragma unroll
    for (int j = 0; j < 4; j++) acc[i][j] = (floatx4){0.f,0.f,0.f,0.f};

  for (int k0 = 0; k0 < 512; k0 += 32) {
    __syncthreads();
    #pragma unroll
    for (int cc = 0; cc < 2; cc++) {
      int ch = wave*2 + cc;
      async16(Ab + (size_t)(ch*16 + srow)*512 + k0 + scol, &As[ch*512]);
      async16(Bb + (size_t)(ch*16 + srow)*512 + k0 + scol, &Bs[ch*512]);
    }
    __syncthreads();
    short8 af[4], bf[4];
    #pragma unroll
    for (int f = 0; f < 4; f++) {
      af[f] = *(const short8*)&As[(wr*64 + f*16 + fm)*32 + fq*8];
      bf[f] = *(const short8*)&Bs[(wc*64 + f*16 + fm)*32 + fq*8];
    }
    #pragma unroll
    for (int fr = 0; fr < 4; fr++) {
      if (vsw[fr]) {
        #pragma unroll
        for (int fc = 0; fc < 4; fc++)
          acc[fr][fc] = __builtin_amdgcn_mfma_f32_16x16x32_bf16(bf[fc], af[fr], acc[fr][fc], 0, 0, 0);
      } else {
        #pragma unroll
        for (int fc = 0; fc < 4; fc++)
          acc[fr][fc] = __builtin_amdgcn_mfma_f32_16x16x32_bf16(af[fr], bf[fc], acc[fr][fc], 0, 0, 0);
      }
    }
  }

  #pragma unroll
  for (int fr = 0; fr < 4; fr++) {
    const int ob     = o0 + wr*64 + fr*16;
    const int head   = ob / 192;
    const int rem    = ob % 192;
    const int region = rem >> 6;             // 0=q 1=k 2=v
    const int bhh    = b*8 + head;
    #pragma unroll
    for (int fc = 0; fc < 4; fc++) {
      if (region == 0) {
        const int i = n0 + wc*64 + fc*16 + fm;
        const int dsub = (rem & 63) + fq*4;
        unsigned short t4[4];
        #pragma unroll
        for (int r = 0; r < 4; r++) t4[r] = f2bf(acc[fr][fc][r] * 0.18033688f);
        uint2 o; o.x = pack2(t4[0], t4[1]); o.y = pack2(t4[2], t4[3]);
        *(uint2*)&q_t[((size_t)bhh*4096 + i)*64 + dsub] = o;
      } else if (region == 1) {
        const int i = n0 + wc*64 + fc*16 + fm;
        const int dsub = (rem & 63) + fq*4;
        unsigned short t4[4];
        #pragma unroll
        for (int r = 0; r < 4; r++) t4[r] = f2bf(acc[fr][fc][r]);
        uint2 o; o.x = pack2(t4[0], t4[1]); o.y = pack2(t4[2], t4[3]);
        *(uint2*)&k_t[((size_t)bhh*4096 + i)*64 + dsub] = o;
      } else {
        const int dsub = (rem & 63) + fm;
        const int tok0 = n0 + wc*64 + fc*16 + fq*4;
        unsigned short t4[4];
        #pragma unroll
        for (int r = 0; r < 4; r++) t4[r] = f2bf(acc[fr][fc][r]);
        uint2 o; o.x = pack2(t4[0], t4[1]); o.y = pack2(t4[2], t4[3]);
        *(uint2*)&v_[((size_t)bhh*64 + dsub)*4096 + tok0] = o;
      }
    }
  }
}

// ---------------------------------------------------------------- proj GEMM
// R7 config: BK=32, no XCD swizzle.
__global__ __launch_bounds__(256, 2)
void proj_gemm(const unsigned short* __restrict__ A,     // wproj [512][512]
               const unsigned short* __restrict__ Bt,    // hout_t [B][4096][512]
               float* __restrict__ outp,
               const float* __restrict__ xres,
               const float* __restrict__ pbias) {
  __shared__ __align__(16) unsigned short As[64*32];
  __shared__ __align__(16) unsigned short Bs[128*32];
  const int b   = blockIdx.z;
  const int n0  = blockIdx.x * 128;
  const int o0  = blockIdx.y * 64;
  const int tid = threadIdx.x;
  const int wave = tid >> 6, lane = tid & 63;
  const int wr = wave >> 1, wc = wave & 1;
  const int fm = lane & 15, fq = lane >> 4;
  const int srow = lane >> 2, scol = (lane & 3) * 8;

  const unsigned short* Ab = A + (size_t)o0 * 512;
  const unsigned short* Bb = Bt + ((size_t)b*4096 + n0) * 512;

  floatx4 acc[2][4];
  #pragma unroll
  for (int i = 0; i < 2; i++)
    #pragma unroll
    for (int j = 0; j < 4; j++) acc[i][j] = (floatx4){0.f,0.f,0.f,0.f};

  for (int k0 = 0; k0 < 512; k0 += 32) {
    __syncthreads();
    async16(Ab + (size_t)(wave*16 + srow)*512 + k0 + scol, &As[wave*512]);
    #pragma unroll
    for (int cc = 0; cc < 2; cc++) {
      int ch = wave*2 + cc;
      async16(Bb + (size_t)(ch*16 + srow)*512 + k0 + scol, &Bs[ch*512]);
    }
    __syncthreads();
    short8 af[2], bf[4];
    #pragma unroll
    for (int f = 0; f < 2; f++)
      af[f] = *(const short8*)&As[(wr*32 + f*16 + fm)*32 + fq*8];
    #pragma unroll
    for (int f = 0; f < 4; f++)
      bf[f] = *(const short8*)&Bs[(wc*64 + f*16 + fm)*32 + fq*8];
    #pragma unroll
    for (int fr = 0; fr < 2; fr++)
      #pragma unroll
      for (int fc = 0; fc < 4; fc++)
        acc[fr][fc] = __builtin_amdgcn_mfma_f32_16x16x32_bf16(af[fr], bf[fc], acc[fr][fc], 0, 0, 0);
  }

  #pragma unroll
  for (int fr = 0; fr < 2; fr++)
    #pragma unroll
    for (int fc = 0; fc < 4; fc++) {
      const int i = n0 + wc*64 + fc*16 + fm;
      #pragma unroll
      for (int r = 0; r < 4; r++) {
        const int o = o0 + wr*32 + fr*16 + fq*4 + r;
        const size_t idx = ((size_t)b*512 + o)*4096 + i;
        outp[idx] = xres[idx] + pbias[o] + acc[fr][fc][r];
      }
    }
}

// ---------------------------------------------------------------- attention
// R7 structure (best measured: attn 73.0 us / total 193.7 us). Pipelined
// QK-ahead, full-rate 32x32x16 PV via permlane32_swap P-layout fix, scalar
// VALU l-accumulate (two independent chains; packed-add asm serialized them:
// R8), reg-staged K/V double-buffer with [64][72] pad (0 bank conflicts),
// 64 q-rows/wave, launch_bounds(256,2).
// CLOSED LANES (do not retry without new evidence):
//  - occupancy >2 blocks/CU: R1/R6 spill (184-reg wave > 170 cap);
//    R10 (32-row waves, fits at 26% occ) regresses -- staging doubles,
//    pipeline depth halves. Structure is dependency-bound, not wave-starved.
//  - setprio around MFMA: fences the interleave (R4, -8%).
//  - l via P x ones MFMA: loads the scarcer matrix pipe (R5, -5%).
//  - BK=64 GEMMs (R8), XCD swizzle on L2-resident GEMMs (R9).

__device__ __forceinline__ void plswap(unsigned &a, unsigned &b) {
  asm("v_permlane32_swap_b32 %0, %1" : "+v"(a), "+v"(b));
}

__device__ __forceinline__ floatx16 qk4(const short8* kf, const short8* qf) {
  const floatx16 z16 = {0.f,0.f,0.f,0.f,0.f,0.f,0.f,0.f,
                        0.f,0.f,0.f,0.f,0.f,0.f,0.f,0.f};
  floatx16 st = __builtin_amdgcn_mfma_f32_32x32x16_bf16(kf[0], qf[0], z16, 0, 0, 0);
  #pragma unroll
  for (int kc = 1; kc < 4; kc++)
    st = __builtin_amdgcn_mfma_f32_32x32x16_bf16(kf[kc], qf[kc], st, 0, 0, 0);
  return st;
}

__device__ __forceinline__ void sm8(const floatx16 st, unsigned* pk, float2& lp) {
  #pragma unroll
  for (int rp = 0; rp < 8; rp++) {
    float p0 = fast_exp2(st[2*rp]);
    float p1 = fast_exp2(st[2*rp + 1]);
    lp.x += p0; lp.y += p1;
    unsigned r;
    asm("v_cvt_pk_bf16_f32 %0, %1, %2" : "=v"(r) : "v"(p0), "v"(p1));
    pk[rp] = r;
  }
}

// PV over one 32-j block: O[i][d] += sum_j P[i][j] V[j][d], two K=16 MFMAs
// per dn. vA = V[j 0..15][d], vB = V[j 16..31][d] B-frags.
__device__ __forceinline__ void pv16(const unsigned* pk,
                                     const short8 vA0, const short8 vA1,
                                     const short8 vB0, const short8 vB1,
                                     floatx16* o) {
  unsigned a0 = pk[0], a2 = pk[2]; plswap(a0, a2);
  unsigned a1 = pk[1], a3 = pk[3]; plswap(a1, a3);
  unsigned b0 = pk[4], b2 = pk[6]; plswap(b0, b2);
  unsigned b1 = pk[5], b3 = pk[7]; plswap(b1, b3);
  union { unsigned u[4]; short8 s; } lo, hi;
  lo.u[0] = a0; lo.u[1] = a1; lo.u[2] = a2; lo.u[3] = a3;
  hi.u[0] = b0; hi.u[1] = b1; hi.u[2] = b2; hi.u[3] = b3;
  o[0] = __builtin_amdgcn_mfma_f32_32x32x16_bf16(lo.s, vA0, o[0], 0, 0, 0);
  o[0] = __builtin_amdgcn_mfma_f32_32x32x16_bf16(hi.s, vB0, o[0], 0, 0, 0);
  o[1] = __builtin_amdgcn_mfma_f32_32x32x16_bf16(lo.s, vA1, o[1], 0, 0, 0);
  o[1] = __builtin_amdgcn_mfma_f32_32x32x16_bf16(hi.s, vB1, o[1], 0, 0, 0);
}

template <int NSPLIT>
__global__ __launch_bounds__(256, 2)
void attn_kernel(const unsigned short* __restrict__ q_t,
                 const unsigned short* __restrict__ k_t,
                 const unsigned short* __restrict__ v_,
                 unsigned short* __restrict__ hout_t,
                 unsigned short* __restrict__ o_part,
                 float* __restrict__ l_part) {
  __shared__ __align__(16) unsigned short Ks[2][64*72];   // [j][k], +pad
  __shared__ __align__(16) unsigned short Vs[2][64*72];   // [d][j] linear, +pad

  const int bh  = blockIdx.x;
  const int q0  = blockIdx.y * 256;
  const int js  = (NSPLIT > 1) ? blockIdx.z : 0;
  const int nt  = 64 / NSPLIT;
  const int jbase = js * (4096 / NSPLIT);
  const int tid = threadIdx.x;
  const int wave = tid >> 6, lane = tid & 63;
  const int ln = lane & 31, h = lane >> 5;

  // Q B-frags (32x32x16): token i = q0 + wave*64 + ih*32 + ln
  short8 qf[2][4];
  #pragma unroll
  for (int ih = 0; ih < 2; ih++) {
    const unsigned short* qrow = q_t + ((size_t)bh*4096 + q0 + wave*64 + ih*32 + ln)*64;
    #pragma unroll
    for (int kc = 0; kc < 4; kc++)
      qf[ih][kc] = *(const short8*)(qrow + kc*16 + h*8);
  }

  const floatx16 z16 = {0.f,0.f,0.f,0.f,0.f,0.f,0.f,0.f,
                        0.f,0.f,0.f,0.f,0.f,0.f,0.f,0.f};
  floatx16 o_acc[2][2];   // [ih][dn]
  #pragma unroll
  for (int ih = 0; ih < 2; ih++) { o_acc[ih][0] = z16; o_acc[ih][1] = z16; }
  float2 lp0 = {0.f, 0.f}, lp1 = {0.f, 0.f};   // per-lane denominators

  const int sr = tid >> 3;          // 0..31
  const int sc = (tid & 7) * 8;     // source 8-short chunk
  const unsigned short* kbase = k_t + (size_t)bh*262144;
  const unsigned short* vbase = v_  + (size_t)bh*262144;

  // preload tile 0 into registers
  uint4 kr0 = *(const uint4*)&kbase[(size_t)(jbase + sr)*64 + sc];
  uint4 kr1 = *(const uint4*)&kbase[(size_t)(jbase + sr + 32)*64 + sc];
  uint4 vr0 = *(const uint4*)&vbase[(size_t)sr*4096 + jbase + sc];
  uint4 vr1 = *(const uint4*)&vbase[(size_t)(sr+32)*4096 + jbase + sc];

  for (int it = 0; it < nt; it++) {
    unsigned short* Kc = Ks[it & 1];
    unsigned short* Vc = Vs[it & 1];
    *(uint4*)&Kc[sr*72 + sc]      = kr0;
    *(uint4*)&Kc[(sr+32)*72 + sc] = kr1;
    *(uint4*)&Vc[sr*72 + sc]      = vr0;
    *(uint4*)&Vc[(sr+32)*72 + sc] = vr1;
    __syncthreads();

    // issue next tile's global loads (latency hidden behind compute)
    {
      int itn = it + 1; if (itn == nt) itn = 0;
      const int jn = jbase + itn * 64;
      kr0 = *(const uint4*)&kbase[(size_t)(jn + sr)*64 + sc];
      kr1 = *(const uint4*)&kbase[(size_t)(jn + sr + 32)*64 + sc];
      vr0 = *(const uint4*)&vbase[(size_t)sr*4096 + jn + sc];
      vr1 = *(const uint4*)&vbase[(size_t)(sr+32)*4096 + jn + sc];
    }

    // ---- mj=0 frags
    short8 kf0[4];
    #pragma unroll
    for (int kc = 0; kc < 4; kc++)
      kf0[kc] = *(const short8*)&Kc[(0*32 + ln)*72 + kc*16 + h*8];
    short8 vA0[2], vB0[2];   // [dn], j 0..15 / 16..31 of mj=0
    #pragma unroll
    for (int dn = 0; dn < 2; dn++) {
      vA0[dn] = *(const short8*)&Vc[(dn*32 + ln)*72 + 0*32 + h*8];
      vB0[dn] = *(const short8*)&Vc[(dn*32 + ln)*72 + 0*32 + 16 + h*8];
    }

    // prologue: QK(mj0, ih0)
    floatx16 stA = qk4(kf0, qf[0]);

    // step 0: QK(mj0,ih1) || softmax(stA) ; PV -> o_acc[0]
    floatx16 stB = qk4(kf0, qf[1]);
    unsigned pkA[8];
    sm8(stA, pkA, lp0);
    pv16(pkA, vA0[0], vA0[1], vB0[0], vB0[1], o_acc[0]);

    // step 1: mj=1 K-frags; QK(mj1,ih0) || softmax(stB) ; PV -> o_acc[1]
    short8 kf1[4];
    #pragma unroll
    for (int kc = 0; kc < 4; kc++)
      kf1[kc] = *(const short8*)&Kc[(1*32 + ln)*72 + kc*16 + h*8];
    floatx16 stC = qk4(kf1, qf[0]);
    unsigned pkB[8];
    sm8(stB, pkB, lp1);
    pv16(pkB, vA0[0], vA0[1], vB0[0], vB0[1], o_acc[1]);

    // step 2: mj=1 V-frags; QK(mj1,ih1) || softmax(stC) ; PV -> o_acc[0]
    short8 vA1[2], vB1[2];
    #pragma unroll
    for (int dn = 0; dn < 2; dn++) {
      vA1[dn] = *(const short8*)&Vc[(dn*32 + ln)*72 + 1*32 + h*8];
      vB1[dn] = *(const short8*)&Vc[(dn*32 + ln)*72 + 1*32 + 16 + h*8];
    }
    floatx16 stD = qk4(kf1, qf[1]);
    unsigned pkC[8];
    sm8(stC, pkC, lp0);
    pv16(pkC, vA1[0], vA1[1], vB1[0], vB1[1], o_acc[0]);

    // step 3 (tail): softmax(stD) ; PV -> o_acc[1]
    unsigned pkD[8];
    sm8(stD, pkD, lp1);
    pv16(pkD, vA1[0], vA1[1], vB1[0], vB1[1], o_acc[1]);
  }

  // column sums complete within lane pairs (h=0/1)
  float l0 = lp0.x + lp0.y;
  float l1 = lp1.x + lp1.y;
  l0 += __shfl_xor(l0, 32, 64);
  l1 += __shfl_xor(l1, 32, 64);

  if (NSPLIT > 1) {
    #pragma unroll
    for (int ih = 0; ih < 2; ih++) {
      unsigned short* op = o_part +
          (((size_t)(js*16 + bh)*4096 + q0 + wave*64 + ih*32) * 64);
      #pragma unroll
      for (int r = 0; r < 16; r++) {
        const int il = (r & 3) + 8*(r >> 2) + 4*h;   // token row within 32
        op[(size_t)il*64 + ln]      = f2bf(o_acc[ih][0][r]);
        op[(size_t)il*64 + 32 + ln] = f2bf(o_acc[ih][1][r]);
      }
    }
    if (lane < 32) {
      l_part[(size_t)(js*16 + bh)*4096 + q0 + wave*64 + lane]      = l0;
      l_part[(size_t)(js*16 + bh)*4096 + q0 + wave*64 + 32 + lane] = l1;
    }
  } else {
    const float linv0 = 1.f / l0;
    const float linv1 = 1.f / l1;
    const int bb = bh >> 3;
    const int cb = (bh & 7) * 64;
    #pragma unroll
    for (int ih = 0; ih < 2; ih++) {
      #pragma unroll
      for (int r = 0; r < 16; r++) {
        const int il = (r & 3) + 8*(r >> 2) + 4*h;
        const float inv = __shfl(ih ? linv1 : linv0, il, 64);
        const int i = q0 + wave*64 + ih*32 + il;
        unsigned short* dst = &hout_t[((size_t)bb*4096 + i)*512 + cb + ln];
        dst[0]  = f2bf(o_acc[ih][0][r] * inv);
        dst[32] = f2bf(o_acc[ih][1][r] * inv);
      }
    }
  }
}

// combine: hout = (O0+O1)/(l0+l1), bf16 token-major
__global__ void attn_combine(const unsigned short* __restrict__ o_part,
                             const float* __restrict__ l_part,
                             unsigned short* __restrict__ hout_t) {
  const int bh = blockIdx.x;
  const int i0 = blockIdx.y * 64;
  const int t  = threadIdx.x;
  const int d4 = (t & 15) * 4;
  const int il = t >> 4;
  const int bb = bh >> 3;
  const int cb = (bh & 7) * 64;
  const size_t JS = (size_t)16 * 4096 * 64;   // js stride in o_part
  #pragma unroll
  for (int p = 0; p < 4; p++) {
    const int i = i0 + p*16 + il;
    const size_t ob = ((size_t)bh*4096 + i)*64 + d4;
    uint2 a = *(const uint2*)&o_part[ob];
    uint2 b = *(const uint2*)&o_part[ob + JS];
    const size_t lb = (size_t)bh*4096 + i;
    const float inv = 1.f / (l_part[lb] + l_part[lb + 65536]);
    float o0 = (bf2f((unsigned short)(a.x & 0xffff)) + bf2f((unsigned short)(b.x & 0xffff))) * inv;
    float o1 = (bf2f((unsigned short)(a.x >> 16))    + bf2f((unsigned short)(b.x >> 16)))    * inv;
    float o2 = (bf2f((unsigned short)(a.y & 0xffff)) + bf2f((unsigned short)(b.y & 0xffff))) * inv;
    float o3 = (bf2f((unsigned short)(a.y >> 16))    + bf2f((unsigned short)(b.y >> 16)))    * inv;
    uint2 w;
    w.x = pack2(f2bf(o0), f2bf(o1));
    w.y = pack2(f2bf(o2), f2bf(o3));
    *(uint2*)&hout_t[((size_t)bb*4096 + i)*512 + cb + d4] = w;
  }
}

// ---------------------------------------------------------------- launcher
extern "C" void kernel_launch(void* const* d_in, const int* in_sizes, int n_in,
                              void* d_out, int out_size, void* d_ws, size_t ws_size,
                              hipStream_t stream) {
  (void)in_sizes; (void)n_in; (void)out_size;
  const float* x      = (const float*)d_in[0];
  const float* qkv_w  = (const float*)d_in[1];
  const float* proj_w = (const float*)d_in[2];
  const float* proj_b = (const float*)d_in[3];
  const float* gn_w   = (const float*)d_in[4];
  const float* gn_b   = (const float*)d_in[5];
  float* out = (float*)d_out;

  char* ws = (char*)d_ws;
  unsigned short* h_t   = (unsigned short*)(ws);                      // 8 MB, reused as hout_t
  unsigned short* q_t   = (unsigned short*)(ws + ((size_t)8  << 20));
  unsigned short* k_t   = (unsigned short*)(ws + ((size_t)16 << 20));
  unsigned short* v_    = (unsigned short*)(ws + ((size_t)24 << 20));
  unsigned short* wqkv  = (unsigned short*)(ws + ((size_t)32 << 20));
  unsigned short* wproj = (unsigned short*)(ws + ((size_t)34 << 20));
  float2* stats_p       = (float2*)(ws + ((size_t)35 << 20));          // 4 KB
  unsigned short* o_part = (unsigned short*)(ws + ((size_t)36 << 20)); // 16 MB
  float* l_part          = (float*)(ws + ((size_t)52 << 20));          // 512 KB
  unsigned short* hout_t = h_t;

  const bool split = ws_size >= (((size_t)52 << 20) + ((size_t)1 << 19));

  setup_kernel<<<dim3(1536), dim3(256), 0, stream>>>(x, stats_p, qkv_w, wqkv, proj_w, wproj);
  gn_apply_t<<<dim3(64, 8, 2), dim3(256), 0, stream>>>(x, stats_p, gn_w, gn_b, h_t);
  qkv_gemm<<<dim3(32, 12, 2), dim3(256), 0, stream>>>(wqkv, h_t, q_t, k_t, v_);
  if (split) {
    attn_kernel<2><<<dim3(16, 16, 2), dim3(256), 0, stream>>>(q_t, k_t, v_, nullptr,
                                                              o_part, l_part);
    attn_combine<<<dim3(16, 64), dim3(256), 0, stream>>>(o_part, l_part, hout_t);
  } else {
    attn_kernel<1><<<dim3(16, 16), dim3(256), 0, stream>>>(q_t, k_t, v_, hout_t,
                                                           nullptr, nullptr);
  }
  proj_gemm<<<dim3(32, 8, 2), dim3(256), 0, stream>>>(wproj, hout_t, out, x, proj_b);
}

// Round 12
// 189.180 us; speedup vs baseline: 1.1073x; 1.0347x over previous
//
#include <hip/hip_runtime.h>
#include <math.h>

typedef __attribute__((ext_vector_type(8))) short short8;
typedef __attribute__((ext_vector_type(4))) float floatx4;
typedef __attribute__((ext_vector_type(16))) float floatx16;

__device__ __forceinline__ unsigned short f2bf(float f) {
  union { float f; unsigned int u; } v; v.f = f;
  unsigned int r = v.u + 0x7fffu + ((v.u >> 16) & 1u);
  return (unsigned short)(r >> 16);
}

__device__ __forceinline__ float bf2f(unsigned short h) {
  union { unsigned int u; float f; } v; v.u = ((unsigned int)h) << 16;
  return v.f;
}

__device__ __forceinline__ unsigned int pack2(unsigned short a, unsigned short b) {
  return (unsigned int)a | ((unsigned int)b << 16);
}

__device__ __forceinline__ float fast_exp2(float x) {
#if __has_builtin(__builtin_amdgcn_exp2f)
  return __builtin_amdgcn_exp2f(x);
#else
  return exp2f(x);
#endif
}

// async global->LDS, 16B per lane. LDS dest is wave-uniform base + lane*16.
__device__ __forceinline__ void async16(const unsigned short* gp, unsigned short* lp) {
  __builtin_amdgcn_global_load_lds(
      (__attribute__((address_space(1))) void*)(gp),
      (__attribute__((address_space(3))) void*)(lp), 16, 0, 0);
}

// ------------------------------------------------- setup: GN stats + w casts
// Stats parallelized: 512 blocks (8 sub-blocks per (b,group), 128KB each)
// write float2{sum, sumsq} partials; gn_apply_t folds the 8 partials.
__global__ void setup_kernel(const float* __restrict__ x, float2* __restrict__ stats_p,
                             const float* __restrict__ qkv_w, unsigned short* __restrict__ wqkv,
                             const float* __restrict__ proj_w, unsigned short* __restrict__ wproj) {
  if (blockIdx.x < 512) {
    const int bid = blockIdx.x;
    const int bg  = bid >> 3;
    const int sub = bid & 7;
    const float4* p = (const float4*)(x + (size_t)bg * 65536 + (size_t)sub * 8192);
    float s = 0.f, ss = 0.f;
    #pragma unroll
    for (int i = 0; i < 8; i++) {
      float4 v = p[threadIdx.x + i*256];
      s  += v.x + v.y + v.z + v.w;
      ss += v.x*v.x + v.y*v.y + v.z*v.z + v.w*v.w;
    }
    #pragma unroll
    for (int off = 32; off >= 1; off >>= 1) {
      s  += __shfl_xor(s,  off, 64);
      ss += __shfl_xor(ss, off, 64);
    }
    __shared__ float red[2][4];
    int wv = threadIdx.x >> 6;
    if ((threadIdx.x & 63) == 0) { red[0][wv] = s; red[1][wv] = ss; }
    __syncthreads();
    if (threadIdx.x == 0) {
      s  = red[0][0] + red[0][1] + red[0][2] + red[0][3];
      ss = red[1][0] + red[1][1] + red[1][2] + red[1][3];
      stats_p[bid] = make_float2(s, ss);
    }
  } else {
    int i = (blockIdx.x - 512) * 256 + threadIdx.x;
    const float* s; unsigned short* d;
    if (i < 196608) { s = qkv_w; d = wqkv; }
    else { i -= 196608; s = proj_w; d = wproj; }
    float4 vv = ((const float4*)s)[i];
    uint2 o;
    o.x = pack2(f2bf(vv.x), f2bf(vv.y));
    o.y = pack2(f2bf(vv.z), f2bf(vv.w));
    ((uint2*)d)[i] = o;
  }
}

// normalize + cast bf16 + transpose to token-major h_t[B][HW][C]
__global__ void gn_apply_t(const float* __restrict__ x, const float2* __restrict__ stats_p,
                           const float* __restrict__ gw, const float* __restrict__ gb,
                           unsigned short* __restrict__ h_t) {
  __shared__ __align__(16) unsigned short tile[64][72];
  const int b = blockIdx.z, c0 = blockIdx.y * 64, hw0 = blockIdx.x * 64;
  const int t = threadIdx.x;
  {
    const int cl = t >> 2;
    const int hs = (t & 3) * 16;
    const int c  = c0 + cl;
    const int g  = c >> 4;
    const float2* sp = stats_p + ((size_t)(b*32 + g) << 3);
    float s = 0.f, ss = 0.f;
    #pragma unroll
    for (int k = 0; k < 8; k++) { float2 v = sp[k]; s += v.x; ss += v.y; }
    const float mean = s * (1.f/65536.f);
    const float var  = ss * (1.f/65536.f) - mean*mean;
    const float rstd = rsqrtf(var + 1e-5f);
    const float w  = gw[c] * rstd;
    const float bb = gb[c] - mean * w;
    const float4* src = (const float4*)(x + ((size_t)(b*512 + c))*4096 + hw0 + hs);
    #pragma unroll
    for (int i = 0; i < 4; i++) {
      float4 vv = src[i];
      unsigned short* d = &tile[cl][hs + i*4];
      d[0] = f2bf(vv.x*w + bb); d[1] = f2bf(vv.y*w + bb);
      d[2] = f2bf(vv.z*w + bb); d[3] = f2bf(vv.w*w + bb);
    }
  }
  __syncthreads();
  {
    const int hwl = t >> 2;
    const int cs  = (t & 3) * 16;
    uint4 w0, w1;
    w0.x = pack2(tile[cs+ 0][hwl], tile[cs+ 1][hwl]);
    w0.y = pack2(tile[cs+ 2][hwl], tile[cs+ 3][hwl]);
    w0.z = pack2(tile[cs+ 4][hwl], tile[cs+ 5][hwl]);
    w0.w = pack2(tile[cs+ 6][hwl], tile[cs+ 7][hwl]);
    w1.x = pack2(tile[cs+ 8][hwl], tile[cs+ 9][hwl]);
    w1.y = pack2(tile[cs+10][hwl], tile[cs+11][hwl]);
    w1.z = pack2(tile[cs+12][hwl], tile[cs+13][hwl]);
    w1.w = pack2(tile[cs+14][hwl], tile[cs+15][hwl]);
    unsigned short* dst = h_t + ((size_t)(b*4096 + hw0 + hwl))*512 + c0 + cs;
    *(uint4*)dst       = w0;
    *(uint4*)(dst + 8) = w1;
  }
}

// ---------------------------------------------------------------- QKV GEMM
// R7 fragment layout + T3-minimum 2-phase staging: LDS double-buffered,
// tile t+1's global_load_lds issued AFTER the barrier and BEFORE computing
// tile t -> load latency hides under the MFMA phase; ONE barrier per K-iter
// (the single-buffer version exposed vmcnt(0) drain every iteration).
// LDS 32KB x 3 blocks/CU = 96KB. BK=32 (BK=64 regressed: R8); no XCD
// swizzle (regressed: R9).
__global__ __launch_bounds__(256, 3)
void qkv_gemm(const unsigned short* __restrict__ A,
              const unsigned short* __restrict__ Bt,
              unsigned short* __restrict__ q_t,
              unsigned short* __restrict__ k_t,
              unsigned short* __restrict__ v_) {
  __shared__ __align__(16) unsigned short As[2][128*32];
  __shared__ __align__(16) unsigned short Bs[2][128*32];
  const int b   = blockIdx.z;
  const int n0  = blockIdx.x * 128;
  const int o0  = blockIdx.y * 128;
  const int tid = threadIdx.x;
  const int wave = tid >> 6, lane = tid & 63;
  const int wr = wave >> 1, wc = wave & 1;
  const int fm = lane & 15, fq = lane >> 4;
  const int srow = lane >> 2, scol = (lane & 3) * 8;

  const unsigned short* Ab = A + (size_t)o0 * 512;
  const unsigned short* Bb = Bt + ((size_t)b*4096 + n0) * 512;

  bool vsw[4];
  #pragma unroll
  for (int fr = 0; fr < 4; fr++) {
    const int ob = o0 + wr*64 + fr*16;
    vsw[fr] = ((ob % 192) >> 6) == 2;
  }

  floatx4 acc[4][4];
  #pragma unroll
  for (int i = 0; i < 4; i++)
    #pragma unroll
    for (int j = 0; j < 4; j++) acc[i][j] = (floatx4){0.f,0.f,0.f,0.f};

  // prologue: stage K-tile 0 into buffer 0
  #pragma unroll
  for (int cc = 0; cc < 2; cc++) {
    int ch = wave*2 + cc;
    async16(Ab + (size_t)(ch*16 + srow)*512 + scol, &As[0][ch*512]);
    async16(Bb + (size_t)(ch*16 + srow)*512 + scol, &Bs[0][ch*512]);
  }

  for (int it = 0; it < 16; it++) {
    __syncthreads();   // drains vmcnt: buf[it&1] staged; prior reads done
    if (it < 15) {
      const int k0 = (it + 1) * 32;
      const int nb = (it + 1) & 1;
      #pragma unroll
      for (int cc = 0; cc < 2; cc++) {
        int ch = wave*2 + cc;
        async16(Ab + (size_t)(ch*16 + srow)*512 + k0 + scol, &As[nb][ch*512]);
        async16(Bb + (size_t)(ch*16 + srow)*512 + k0 + scol, &Bs[nb][ch*512]);
      }
    }
    const unsigned short* Ac = As[it & 1];
    const unsigned short* Bc = Bs[it & 1];
    short8 af[4], bf[4];
    #pragma unroll
    for (int f = 0; f < 4; f++) {
      af[f] = *(const short8*)&Ac[(wr*64 + f*16 + fm)*32 + fq*8];
      bf[f] = *(const short8*)&Bc[(wc*64 + f*16 + fm)*32 + fq*8];
    }
    #pragma unroll
    for (int fr = 0; fr < 4; fr++) {
      if (vsw[fr]) {
        #pragma unroll
        for (int fc = 0; fc < 4; fc++)
          acc[fr][fc] = __builtin_amdgcn_mfma_f32_16x16x32_bf16(bf[fc], af[fr], acc[fr][fc], 0, 0, 0);
      } else {
        #pragma unroll
        for (int fc = 0; fc < 4; fc++)
          acc[fr][fc] = __builtin_amdgcn_mfma_f32_16x16x32_bf16(af[fr], bf[fc], acc[fr][fc], 0, 0, 0);
      }
    }
  }

  #pragma unroll
  for (int fr = 0; fr < 4; fr++) {
    const int ob     = o0 + wr*64 + fr*16;
    const int head   = ob / 192;
    const int rem    = ob % 192;
    const int region = rem >> 6;             // 0=q 1=k 2=v
    const int bhh    = b*8 + head;
    #pragma unroll
    for (int fc = 0; fc < 4; fc++) {
      if (region == 0) {
        const int i = n0 + wc*64 + fc*16 + fm;
        const int dsub = (rem & 63) + fq*4;
        unsigned short t4[4];
        #pragma unroll
        for (int r = 0; r < 4; r++) t4[r] = f2bf(acc[fr][fc][r] * 0.18033688f);
        uint2 o; o.x = pack2(t4[0], t4[1]); o.y = pack2(t4[2], t4[3]);
        *(uint2*)&q_t[((size_t)bhh*4096 + i)*64 + dsub] = o;
      } else if (region == 1) {
        const int i = n0 + wc*64 + fc*16 + fm;
        const int dsub = (rem & 63) + fq*4;
        unsigned short t4[4];
        #pragma unroll
        for (int r = 0; r < 4; r++) t4[r] = f2bf(acc[fr][fc][r]);
        uint2 o; o.x = pack2(t4[0], t4[1]); o.y = pack2(t4[2], t4[3]);
        *(uint2*)&k_t[((size_t)bhh*4096 + i)*64 + dsub] = o;
      } else {
        const int dsub = (rem & 63) + fm;
        const int tok0 = n0 + wc*64 + fc*16 + fq*4;
        unsigned short t4[4];
        #pragma unroll
        for (int r = 0; r < 4; r++) t4[r] = f2bf(acc[fr][fc][r]);
        uint2 o; o.x = pack2(t4[0], t4[1]); o.y = pack2(t4[2], t4[3]);
        *(uint2*)&v_[((size_t)bhh*64 + dsub)*4096 + tok0] = o;
      }
    }
  }
}

// ---------------------------------------------------------------- proj GEMM
// T3-minimum 2-phase staging (see qkv note). LDS 24KB x 2 blocks = 48KB.
__global__ __launch_bounds__(256, 2)
void proj_gemm(const unsigned short* __restrict__ A,     // wproj [512][512]
               const unsigned short* __restrict__ Bt,    // hout_t [B][4096][512]
               float* __restrict__ outp,
               const float* __restrict__ xres,
               const float* __restrict__ pbias) {
  __shared__ __align__(16) unsigned short As[2][64*32];
  __shared__ __align__(16) unsigned short Bs[2][128*32];
  const int b   = blockIdx.z;
  const int n0  = blockIdx.x * 128;
  const int o0  = blockIdx.y * 64;
  const int tid = threadIdx.x;
  const int wave = tid >> 6, lane = tid & 63;
  const int wr = wave >> 1, wc = wave & 1;
  const int fm = lane & 15, fq = lane >> 4;
  const int srow = lane >> 2, scol = (lane & 3) * 8;

  const unsigned short* Ab = A + (size_t)o0 * 512;
  const unsigned short* Bb = Bt + ((size_t)b*4096 + n0) * 512;

  floatx4 acc[2][4];
  #pragma unroll
  for (int i = 0; i < 2; i++)
    #pragma unroll
    for (int j = 0; j < 4; j++) acc[i][j] = (floatx4){0.f,0.f,0.f,0.f};

  // prologue: stage K-tile 0 into buffer 0
  async16(Ab + (size_t)(wave*16 + srow)*512 + scol, &As[0][wave*512]);
  #pragma unroll
  for (int cc = 0; cc < 2; cc++) {
    int ch = wave*2 + cc;
    async16(Bb + (size_t)(ch*16 + srow)*512 + scol, &Bs[0][ch*512]);
  }

  for (int it = 0; it < 16; it++) {
    __syncthreads();   // drains vmcnt: buf[it&1] staged; prior reads done
    if (it < 15) {
      const int k0 = (it + 1) * 32;
      const int nb = (it + 1) & 1;
      async16(Ab + (size_t)(wave*16 + srow)*512 + k0 + scol, &As[nb][wave*512]);
      #pragma unroll
      for (int cc = 0; cc < 2; cc++) {
        int ch = wave*2 + cc;
        async16(Bb + (size_t)(ch*16 + srow)*512 + k0 + scol, &Bs[nb][ch*512]);
      }
    }
    const unsigned short* Ac = As[it & 1];
    const unsigned short* Bc = Bs[it & 1];
    short8 af[2], bf[4];
    #pragma unroll
    for (int f = 0; f < 2; f++)
      af[f] = *(const short8*)&Ac[(wr*32 + f*16 + fm)*32 + fq*8];
    #pragma unroll
    for (int f = 0; f < 4; f++)
      bf[f] = *(const short8*)&Bc[(wc*64 + f*16 + fm)*32 + fq*8];
    #pragma unroll
    for (int fr = 0; fr < 2; fr++)
      #pragma unroll
      for (int fc = 0; fc < 4; fc++)
        acc[fr][fc] = __builtin_amdgcn_mfma_f32_16x16x32_bf16(af[fr], bf[fc], acc[fr][fc], 0, 0, 0);
  }

  #pragma unroll
  for (int fr = 0; fr < 2; fr++)
    #pragma unroll
    for (int fc = 0; fc < 4; fc++) {
      const int i = n0 + wc*64 + fc*16 + fm;
      #pragma unroll
      for (int r = 0; r < 4; r++) {
        const int o = o0 + wr*32 + fr*16 + fq*4 + r;
        const size_t idx = ((size_t)b*512 + o)*4096 + i;
        outp[idx] = xres[idx] + pbias[o] + acc[fr][fc][r];
      }
    }
}

// ---------------------------------------------------------------- attention
// R7 structure (best measured: attn 73.0 us, reproduced R11). Pipelined
// QK-ahead, full-rate 32x32x16 PV via permlane32_swap P-layout fix, scalar
// VALU l-accumulate (two independent chains), reg-staged K/V double-buffer
// with [64][72] pad (0 bank conflicts), 64 q-rows/wave, launch_bounds(256,2).
// CLOSED LANES (do not retry without new evidence):
//  - occupancy >2 blocks/CU: R1/R6 spill; R10 (32-row waves) regresses.
//  - setprio around MFMA (R4, -8%); l via P x ones MFMA (R5, -5%);
//    packed-f32 l adds (R8, serializes chains).

__device__ __forceinline__ void plswap(unsigned &a, unsigned &b) {
  asm("v_permlane32_swap_b32 %0, %1" : "+v"(a), "+v"(b));
}

__device__ __forceinline__ floatx16 qk4(const short8* kf, const short8* qf) {
  const floatx16 z16 = {0.f,0.f,0.f,0.f,0.f,0.f,0.f,0.f,
                        0.f,0.f,0.f,0.f,0.f,0.f,0.f,0.f};
  floatx16 st = __builtin_amdgcn_mfma_f32_32x32x16_bf16(kf[0], qf[0], z16, 0, 0, 0);
  #pragma unroll
  for (int kc = 1; kc < 4; kc++)
    st = __builtin_amdgcn_mfma_f32_32x32x16_bf16(kf[kc], qf[kc], st, 0, 0, 0);
  return st;
}

__device__ __forceinline__ void sm8(const floatx16 st, unsigned* pk, float2& lp) {
  #pragma unroll
  for (int rp = 0; rp < 8; rp++) {
    float p0 = fast_exp2(st[2*rp]);
    float p1 = fast_exp2(st[2*rp + 1]);
    lp.x += p0; lp.y += p1;
    unsigned r;
    asm("v_cvt_pk_bf16_f32 %0, %1, %2" : "=v"(r) : "v"(p0), "v"(p1));
    pk[rp] = r;
  }
}

// PV over one 32-j block: O[i][d] += sum_j P[i][j] V[j][d], two K=16 MFMAs
// per dn. vA = V[j 0..15][d], vB = V[j 16..31][d] B-frags.
__device__ __forceinline__ void pv16(const unsigned* pk,
                                     const short8 vA0, const short8 vA1,
                                     const short8 vB0, const short8 vB1,
                                     floatx16* o) {
  unsigned a0 = pk[0], a2 = pk[2]; plswap(a0, a2);
  unsigned a1 = pk[1], a3 = pk[3]; plswap(a1, a3);
  unsigned b0 = pk[4], b2 = pk[6]; plswap(b0, b2);
  unsigned b1 = pk[5], b3 = pk[7]; plswap(b1, b3);
  union { unsigned u[4]; short8 s; } lo, hi;
  lo.u[0] = a0; lo.u[1] = a1; lo.u[2] = a2; lo.u[3] = a3;
  hi.u[0] = b0; hi.u[1] = b1; hi.u[2] = b2; hi.u[3] = b3;
  o[0] = __builtin_amdgcn_mfma_f32_32x32x16_bf16(lo.s, vA0, o[0], 0, 0, 0);
  o[0] = __builtin_amdgcn_mfma_f32_32x32x16_bf16(hi.s, vB0, o[0], 0, 0, 0);
  o[1] = __builtin_amdgcn_mfma_f32_32x32x16_bf16(lo.s, vA1, o[1], 0, 0, 0);
  o[1] = __builtin_amdgcn_mfma_f32_32x32x16_bf16(hi.s, vB1, o[1], 0, 0, 0);
}

template <int NSPLIT>
__global__ __launch_bounds__(256, 2)
void attn_kernel(const unsigned short* __restrict__ q_t,
                 const unsigned short* __restrict__ k_t,
                 const unsigned short* __restrict__ v_,
                 unsigned short* __restrict__ hout_t,
                 unsigned short* __restrict__ o_part,
                 float* __restrict__ l_part) {
  __shared__ __align__(16) unsigned short Ks[2][64*72];   // [j][k], +pad
  __shared__ __align__(16) unsigned short Vs[2][64*72];   // [d][j] linear, +pad

  const int bh  = blockIdx.x;
  const int q0  = blockIdx.y * 256;
  const int js  = (NSPLIT > 1) ? blockIdx.z : 0;
  const int nt  = 64 / NSPLIT;
  const int jbase = js * (4096 / NSPLIT);
  const int tid = threadIdx.x;
  const int wave = tid >> 6, lane = tid & 63;
  const int ln = lane & 31, h = lane >> 5;

  // Q B-frags (32x32x16): token i = q0 + wave*64 + ih*32 + ln
  short8 qf[2][4];
  #pragma unroll
  for (int ih = 0; ih < 2; ih++) {
    const unsigned short* qrow = q_t + ((size_t)bh*4096 + q0 + wave*64 + ih*32 + ln)*64;
    #pragma unroll
    for (int kc = 0; kc < 4; kc++)
      qf[ih][kc] = *(const short8*)(qrow + kc*16 + h*8);
  }

  const floatx16 z16 = {0.f,0.f,0.f,0.f,0.f,0.f,0.f,0.f,
                        0.f,0.f,0.f,0.f,0.f,0.f,0.f,0.f};
  floatx16 o_acc[2][2];   // [ih][dn]
  #pragma unroll
  for (int ih = 0; ih < 2; ih++) { o_acc[ih][0] = z16; o_acc[ih][1] = z16; }
  float2 lp0 = {0.f, 0.f}, lp1 = {0.f, 0.f};   // per-lane denominators

  const int sr = tid >> 3;          // 0..31
  const int sc = (tid & 7) * 8;     // source 8-short chunk
  const unsigned short* kbase = k_t + (size_t)bh*262144;
  const unsigned short* vbase = v_  + (size_t)bh*262144;

  // preload tile 0 into registers
  uint4 kr0 = *(const uint4*)&kbase[(size_t)(jbase + sr)*64 + sc];
  uint4 kr1 = *(const uint4*)&kbase[(size_t)(jbase + sr + 32)*64 + sc];
  uint4 vr0 = *(const uint4*)&vbase[(size_t)sr*4096 + jbase + sc];
  uint4 vr1 = *(const uint4*)&vbase[(size_t)(sr+32)*4096 + jbase + sc];

  for (int it = 0; it < nt; it++) {
    unsigned short* Kc = Ks[it & 1];
    unsigned short* Vc = Vs[it & 1];
    *(uint4*)&Kc[sr*72 + sc]      = kr0;
    *(uint4*)&Kc[(sr+32)*72 + sc] = kr1;
    *(uint4*)&Vc[sr*72 + sc]      = vr0;
    *(uint4*)&Vc[(sr+32)*72 + sc] = vr1;
    __syncthreads();

    // issue next tile's global loads (latency hidden behind compute)
    {
      int itn = it + 1; if (itn == nt) itn = 0;
      const int jn = jbase + itn * 64;
      kr0 = *(const uint4*)&kbase[(size_t)(jn + sr)*64 + sc];
      kr1 = *(const uint4*)&kbase[(size_t)(jn + sr + 32)*64 + sc];
      vr0 = *(const uint4*)&vbase[(size_t)sr*4096 + jn + sc];
      vr1 = *(const uint4*)&vbase[(size_t)(sr+32)*4096 + jn + sc];
    }

    // ---- mj=0 frags
    short8 kf0[4];
    #pragma unroll
    for (int kc = 0; kc < 4; kc++)
      kf0[kc] = *(const short8*)&Kc[(0*32 + ln)*72 + kc*16 + h*8];
    short8 vA0[2], vB0[2];   // [dn], j 0..15 / 16..31 of mj=0
    #pragma unroll
    for (int dn = 0; dn < 2; dn++) {
      vA0[dn] = *(const short8*)&Vc[(dn*32 + ln)*72 + 0*32 + h*8];
      vB0[dn] = *(const short8*)&Vc[(dn*32 + ln)*72 + 0*32 + 16 + h*8];
    }

    // prologue: QK(mj0, ih0)
    floatx16 stA = qk4(kf0, qf[0]);

    // step 0: QK(mj0,ih1) || softmax(stA) ; PV -> o_acc[0]
    floatx16 stB = qk4(kf0, qf[1]);
    unsigned pkA[8];
    sm8(stA, pkA, lp0);
    pv16(pkA, vA0[0], vA0[1], vB0[0], vB0[1], o_acc[0]);

    // step 1: mj=1 K-frags; QK(mj1,ih0) || softmax(stB) ; PV -> o_acc[1]
    short8 kf1[4];
    #pragma unroll
    for (int kc = 0; kc < 4; kc++)
      kf1[kc] = *(const short8*)&Kc[(1*32 + ln)*72 + kc*16 + h*8];
    floatx16 stC = qk4(kf1, qf[0]);
    unsigned pkB[8];
    sm8(stB, pkB, lp1);
    pv16(pkB, vA0[0], vA0[1], vB0[0], vB0[1], o_acc[1]);

    // step 2: mj=1 V-frags; QK(mj1,ih1) || softmax(stC) ; PV -> o_acc[0]
    short8 vA1[2], vB1[2];
    #pragma unroll
    for (int dn = 0; dn < 2; dn++) {
      vA1[dn] = *(const short8*)&Vc[(dn*32 + ln)*72 + 1*32 + h*8];
      vB1[dn] = *(const short8*)&Vc[(dn*32 + ln)*72 + 1*32 + 16 + h*8];
    }
    floatx16 stD = qk4(kf1, qf[1]);
    unsigned pkC[8];
    sm8(stC, pkC, lp0);
    pv16(pkC, vA1[0], vA1[1], vB1[0], vB1[1], o_acc[0]);

    // step 3 (tail): softmax(stD) ; PV -> o_acc[1]
    unsigned pkD[8];
    sm8(stD, pkD, lp1);
    pv16(pkD, vA1[0], vA1[1], vB1[0], vB1[1], o_acc[1]);
  }

  // column sums complete within lane pairs (h=0/1)
  float l0 = lp0.x + lp0.y;
  float l1 = lp1.x + lp1.y;
  l0 += __shfl_xor(l0, 32, 64);
  l1 += __shfl_xor(l1, 32, 64);

  if (NSPLIT > 1) {
    #pragma unroll
    for (int ih = 0; ih < 2; ih++) {
      unsigned short* op = o_part +
          (((size_t)(js*16 + bh)*4096 + q0 + wave*64 + ih*32) * 64);
      #pragma unroll
      for (int r = 0; r < 16; r++) {
        const int il = (r & 3) + 8*(r >> 2) + 4*h;   // token row within 32
        op[(size_t)il*64 + ln]      = f2bf(o_acc[ih][0][r]);
        op[(size_t)il*64 + 32 + ln] = f2bf(o_acc[ih][1][r]);
      }
    }
    if (lane < 32) {
      l_part[(size_t)(js*16 + bh)*4096 + q0 + wave*64 + lane]      = l0;
      l_part[(size_t)(js*16 + bh)*4096 + q0 + wave*64 + 32 + lane] = l1;
    }
  } else {
    const float linv0 = 1.f / l0;
    const float linv1 = 1.f / l1;
    const int bb = bh >> 3;
    const int cb = (bh & 7) * 64;
    #pragma unroll
    for (int ih = 0; ih < 2; ih++) {
      #pragma unroll
      for (int r = 0; r < 16; r++) {
        const int il = (r & 3) + 8*(r >> 2) + 4*h;
        const float inv = __shfl(ih ? linv1 : linv0, il, 64);
        const int i = q0 + wave*64 + ih*32 + il;
        unsigned short* dst = &hout_t[((size_t)bb*4096 + i)*512 + cb + ln];
        dst[0]  = f2bf(o_acc[ih][0][r] * inv);
        dst[32] = f2bf(o_acc[ih][1][r] * inv);
      }
    }
  }
}

// combine: hout = (O0+O1)/(l0+l1), bf16 token-major
__global__ void attn_combine(const unsigned short* __restrict__ o_part,
                             const float* __restrict__ l_part,
                             unsigned short* __restrict__ hout_t) {
  const int bh = blockIdx.x;
  const int i0 = blockIdx.y * 64;
  const int t  = threadIdx.x;
  const int d4 = (t & 15) * 4;
  const int il = t >> 4;
  const int bb = bh >> 3;
  const int cb = (bh & 7) * 64;
  const size_t JS = (size_t)16 * 4096 * 64;   // js stride in o_part
  #pragma unroll
  for (int p = 0; p < 4; p++) {
    const int i = i0 + p*16 + il;
    const size_t ob = ((size_t)bh*4096 + i)*64 + d4;
    uint2 a = *(const uint2*)&o_part[ob];
    uint2 b = *(const uint2*)&o_part[ob + JS];
    const size_t lb = (size_t)bh*4096 + i;
    const float inv = 1.f / (l_part[lb] + l_part[lb + 65536]);
    float o0 = (bf2f((unsigned short)(a.x & 0xffff)) + bf2f((unsigned short)(b.x & 0xffff))) * inv;
    float o1 = (bf2f((unsigned short)(a.x >> 16))    + bf2f((unsigned short)(b.x >> 16)))    * inv;
    float o2 = (bf2f((unsigned short)(a.y & 0xffff)) + bf2f((unsigned short)(b.y & 0xffff))) * inv;
    float o3 = (bf2f((unsigned short)(a.y >> 16))    + bf2f((unsigned short)(b.y >> 16)))    * inv;
    uint2 w;
    w.x = pack2(f2bf(o0), f2bf(o1));
    w.y = pack2(f2bf(o2), f2bf(o3));
    *(uint2*)&hout_t[((size_t)bb*4096 + i)*512 + cb + d4] = w;
  }
}

// ---------------------------------------------------------------- launcher
extern "C" void kernel_launch(void* const* d_in, const int* in_sizes, int n_in,
                              void* d_out, int out_size, void* d_ws, size_t ws_size,
                              hipStream_t stream) {
  (void)in_sizes; (void)n_in; (void)out_size;
  const float* x      = (const float*)d_in[0];
  const float* qkv_w  = (const float*)d_in[1];
  const float* proj_w = (const float*)d_in[2];
  const float* proj_b = (const float*)d_in[3];
  const float* gn_w   = (const float*)d_in[4];
  const float* gn_b   = (const float*)d_in[5];
  float* out = (float*)d_out;

  char* ws = (char*)d_ws;
  unsigned short* h_t   = (unsigned short*)(ws);                      // 8 MB, reused as hout_t
  unsigned short* q_t   = (unsigned short*)(ws + ((size_t)8  << 20));
  unsigned short* k_t   = (unsigned short*)(ws + ((size_t)16 << 20));
  unsigned short* v_    = (unsigned short*)(ws + ((size_t)24 << 20));
  unsigned short* wqkv  = (unsigned short*)(ws + ((size_t)32 << 20));
  unsigned short* wproj = (unsigned short*)(ws + ((size_t)34 << 20));
  float2* stats_p       = (float2*)(ws + ((size_t)35 << 20));          // 4 KB
  unsigned short* o_part = (unsigned short*)(ws + ((size_t)36 << 20)); // 16 MB
  float* l_part          = (float*)(ws + ((size_t)52 << 20));          // 512 KB
  unsigned short* hout_t = h_t;

  const bool split = ws_size >= (((size_t)52 << 20) + ((size_t)1 << 19));

  setup_kernel<<<dim3(1536), dim3(256), 0, stream>>>(x, stats_p, qkv_w, wqkv, proj_w, wproj);
  gn_apply_t<<<dim3(64, 8, 2), dim3(256), 0, stream>>>(x, stats_p, gn_w, gn_b, h_t);
  qkv_gemm<<<dim3(32, 12, 2), dim3(256), 0, stream>>>(wqkv, h_t, q_t, k_t, v_);
  if (split) {
    attn_kernel<2><<<dim3(16, 16, 2), dim3(256), 0, stream>>>(q_t, k_t, v_, nullptr,
                                                              o_part, l_part);
    attn_combine<<<dim3(16, 64), dim3(256), 0, stream>>>(o_part, l_part, hout_t);
  } else {
    attn_kernel<1><<<dim3(16, 16), dim3(256), 0, stream>>>(q_t, k_t, v_, hout_t,
                                                           nullptr, nullptr);
  }
  proj_gemm<<<dim3(32, 8, 2), dim3(256), 0, stream>>>(wproj, hout_t, out, x, proj_b);
}